// Round 4
// baseline (103.477 us; speedup 1.0000x reference)
//
#include <hip/hip_runtime.h>
#include <stdint.h>
#include <stddef.h>

// Problem: out[b][o] = sum_{i,g} spline(x[b][i])[g] * coef[o][i][g]
//   x: (4096, 1024) f32; coef: (1024, 1024, 8) f32; out: (4096, 1024) f32
// == GEMM: A (4096 x 8192) * B^T (1024 x 8192), K = i*8+g.
//
// R4 change: MFMA SHAPE 16x16x32 -> 32x32x16. Measured ceilings: 16x16 =
// 2176 TF (87% peak) vs 32x32 = 2495 TF (99.8%). Same traffic (perimeter-
// determined), same 128-AGPR acc, but -17% matrix floor and HALF the MFMA
// instruction count. Window/barrier/vmcnt discipline is R0's verbatim
// (best measured structure, 57.2us; R1/R2/R3 structural probes all lost).
// Operands pre-shuffled into 32x32x16 fragment images (prep_kernel):
//   frag map: row/col = lane&31, k = (lane>>5)*8 + e  (extends the
//   harness-verified 16x16 convention); C/D: col=lane&31,
//   row=(r&3)+8*(r>>2)+4*(lane>>5)  [m74/m101].
// 256x256 tile, 8 waves, split-K=4; s=0 -> f32 C, s>0 -> bf16 partials.

#define BATCH 4096
#define IN    1024
#define OUTN  1024
#define KDIM  (IN * 8)     // 8192
#define NTT   (KDIM / 64)  // 128 K-tiles of BK=64

typedef __attribute__((ext_vector_type(8)))  short          short8;
typedef __attribute__((ext_vector_type(8)))  unsigned short ushort8;
typedef __attribute__((ext_vector_type(4)))  float          f32x4;
typedef __attribute__((ext_vector_type(16))) float          f32x16;

// ---------- helpers ----------

__device__ __forceinline__ constexpr float Cf(int i) {
    constexpr double end  = 1.0 + 2.0 * 4.0 / 7.0;        // 1 + 8/7
    constexpr double step = (end - (-1.0)) / 11.0;
    return (float)(-1.0 + (double)i * step);
}

__device__ __forceinline__ unsigned short f2bf(float f) {
    unsigned int u = __builtin_bit_cast(unsigned int, f);
    u += 0x7fffu + ((u >> 16) & 1u);      // round-to-nearest-even
    return (unsigned short)(u >> 16);
}

__device__ __forceinline__ float bf2f(unsigned short u) {
    unsigned int v = (unsigned int)u << 16;
    return __builtin_bit_cast(float, v);
}

__device__ __forceinline__ ushort8 spline8(float xt) {
    float v[11];
#pragma unroll
    for (int j = 0; j < 11; ++j)
        v[j] = (xt >= Cf(j) && xt < Cf(j + 1)) ? 1.0f : 0.0f;
#pragma unroll
    for (int k = 1; k <= 3; ++k) {
#pragma unroll
        for (int j = 0; j < 11 - k; ++j) {
            float left  = (xt - Cf(j))         * (1.0f / (Cf(j + k)     - Cf(j)));
            float right = (Cf(j + k + 1) - xt) * (1.0f / (Cf(j + k + 1) - Cf(j + 1)));
            v[j] = left * v[j] + right * v[j + 1];
        }
    }
    ushort8 r;
#pragma unroll
    for (int g = 0; g < 8; ++g) r[g] = f2bf(v[g]);
    return r;
}

typedef const unsigned int __attribute__((address_space(1))) gu32;
typedef unsigned int       __attribute__((address_space(3))) lu32;

__device__ __forceinline__ void gload_lds16(const void* g, void* l) {
    __builtin_amdgcn_global_load_lds((gu32*)g, (lu32*)l, 16, 0, 0);
}

// ---------- kernel 1: fused prep -> A_shuf / B_shuf 32x32x16 images ----------
//
// Image (ushort8 units): [rg = row>>5][kb = k>>4][lane][e], 512 kb total.
// Element (row, i, g): kb = i>>1, lane = (i&1)*32 + (row&31), e = g.
// A: [128 rg][512 kb][64][8]; B: [32 cg][512 kb][64][8].

__global__ void prep_kernel(const float* __restrict__ x, const float* __restrict__ coef,
                            unsigned short* __restrict__ A, unsigned short* __restrict__ B) {
    const int t = threadIdx.x;
    int blk = blockIdx.x;
    if (blk < 4096) {
        // basis: 128 rb x 32 ib blocks; 32 rows x 32 i per block
        const int rb = blk >> 5, ib = blk & 31;
        const int row = rb * 32 + (t & 31);
        const int i0  = ib * 32 + (t >> 5) * 4;
        f32x4 xv = *reinterpret_cast<const f32x4*>(&x[(size_t)row * IN + i0]);
        ushort8 r[4];
#pragma unroll
        for (int j = 0; j < 4; ++j) r[j] = spline8(tanhf(xv[j]));
        const int kb0 = ib * 16 + (t >> 5) * 2;
        ushort8* out = reinterpret_cast<ushort8*>(A)
                     + ((size_t)rb * 512 + kb0) * 64 + (t & 31);
        out[0]  = r[0];   // (kb0,   lane)
        out[32] = r[1];   // (kb0,   lane+32)
        out[64] = r[2];   // (kb0+1, lane)
        out[96] = r[3];   // (kb0+1, lane+32)
    } else {
        // coef cvt: 32 ob x 32 ib blocks; 32 o x 32 i per block
        blk -= 4096;
        const int ob = blk >> 5, ibk = blk & 31;
        const int o  = ob * 32 + (t & 31);
        const int i0 = ibk * 32 + (t >> 5) * 4;
        const f32x4* cin = reinterpret_cast<const f32x4*>(coef);
        ushort8 r[4];
#pragma unroll
        for (int j = 0; j < 4; ++j) {
            f32x4 v0 = cin[((size_t)o * IN + i0 + j) * 2];
            f32x4 v1 = cin[((size_t)o * IN + i0 + j) * 2 + 1];
#pragma unroll
            for (int g = 0; g < 4; ++g) { r[j][g] = f2bf(v0[g]); r[j][4 + g] = f2bf(v1[g]); }
        }
        const int kb0 = ibk * 16 + (t >> 5) * 2;
        ushort8* out = reinterpret_cast<ushort8*>(B)
                     + ((size_t)ob * 512 + kb0) * 64 + (t & 31);
        out[0]  = r[0];
        out[32] = r[1];
        out[64] = r[2];
        out[96] = r[3];
    }
}

// ---------- kernel 2: 256x256 bf16 GEMM, 32x32x16, R0 window discipline ----------
//
// 8 waves (wm=w>>2, wn=w&3), per-wave output 128x64 interleaved across the
// two stage-halves: rows rgl = H*4 + wm*2 + mf2 (mf2 0..1), cols
// cgl = V*4 + wn. acc[H*2+mf2][V] = f32x16. Per K64-tile: 4 kb-steps.
// Windows per tile t (buf c = t%2, n = other):
//  W1: BAR; W(0,0)[aF(H0),bv0]; read bv1(t); stage B1,A1(t+1)->n
//  W2: BAR; W(0,1)[aF,bv1];     read aF<-H1(t); stage B0(t+2)->c
//  W3: BAR; W(1,0)[aF,bv0];     stage A0(t+2)->c; vmcnt(4)
//  W4: BAR(publish t+1); W(1,1)[aF,bv1]; read aF<-H0(t+1), bv0(t+1) from n
// Event stream/wave/tile: 8 gloads. vmcnt(4)@W3 sees [W1:4][W2:2][W3:2]=8
// -> retires W1's 4 (B1/A1 of t+1) before W4's pre-reads; B0/A0(t+2) stay
// in flight. LDS slot-reuse: last read of every slot is lgkm-consumed >=2
// barriers before its re-stage. Identical discipline to the 57.2us R0.

#define LSA0 (&Ls[0][0])
#define LSB0 (&Ls[0][16384])
#define LSA1 (&Ls[1][0])
#define LSB1 (&Ls[1][16384])

template<int NSPLIT>
__global__ __launch_bounds__(512, 2) void gemm_bt(
        const unsigned short* __restrict__ Ashuf,  // [128 rg][512 kb][64][8]
        const unsigned short* __restrict__ Bshuf,  // [32 cg][512 kb][64][8]
        float* __restrict__ C,                     // [4096][1024]
        unsigned short* __restrict__ P) {          // bf16 partials (splits 1..)
    constexpr int NT2 = NTT / NSPLIT;              // K-tiles per block
    static_assert((NT2 & 1) == 0 && NT2 >= 8, "loop assumes even NT2 >= 8");
    __shared__ unsigned short Ls[2][32768];        // 128 KiB

    const int tid  = threadIdx.x;
    const int w    = tid >> 6;                     // 0..7
    const int lane = tid & 63;
    const int wm   = w >> 2, wn = w & 3;
    const int lane8 = lane * 8;

    const int bid  = blockIdx.x;
    const int s    = bid & (NSPLIT - 1);
    const int tile = bid / NSPLIT;                 // 0..63
    const int tm   = tile >> 2, tn = tile & 3;
    const int mb8  = tm * 8;                       // A rg base
    const int nb8  = tn * 8;                       // B cg base
    const int T0   = s * NT2;
    const int brow = tm * 256, bcol = tn * 256;

    // Stage one 16 KiB half (frags fgl = H*4..H*4+3, all 4 kb): wave w
    // covers fgl = H*4 + (w>>1), kb pair = (w&1)*2 + {0,1}. 2 gloads/wave.
#define STAGE_OP(BASE, NB, H, T, LS) do {                                     \
        const int _f   = (H) * 4 + (w >> 1);                                  \
        const int _kbl = (w & 1) * 2;                                         \
        const unsigned short* _g = (BASE) + ((size_t)((NB) + _f) << 18)       \
                  + ((size_t)((T0 + (T)) * 4 + _kbl) << 9) + lane8;           \
        unsigned short* _l = (LS) + ((_f * 4 + _kbl) << 9);                   \
        gload_lds16(_g, _l);                                                  \
        gload_lds16(_g + 512, _l + 512);                                      \
    } while (0)
#define STAGE_A(H, T, LS) STAGE_OP(Ashuf, mb8, H, T, LS)
#define STAGE_B(H, T, LS) STAGE_OP(Bshuf, nb8, H, T, LS)

    // read aF for m-half H: 8 x ds_read_b128 (frags (H*4+wm*2+mf2, k))
#define LDA_HF(H, LS) do {                                                    \
        _Pragma("unroll")                                                     \
        for (int mf2 = 0; mf2 < 2; ++mf2)                                     \
            _Pragma("unroll")                                                 \
            for (int k = 0; k < 4; ++k)                                       \
                aF[mf2][k] = *reinterpret_cast<const short8*>(                \
                    (LS) + ((((H)*4 + wm*2 + mf2) * 4 + k) << 9) + lane8);    \
    } while (0)
    // read bv for n-half V: 4 x ds_read_b128 (frag (V*4+wn, k))
#define LDB_V(DST, V, LS) do {                                                \
        _Pragma("unroll")                                                     \
        for (int k = 0; k < 4; ++k)                                           \
            DST[k] = *reinterpret_cast<const short8*>(                        \
                (LS) + ((((V)*4 + wn) * 4 + k) << 9) + lane8);                \
    } while (0)

    f32x16 acc[4][2] = {};                         // [H*2+mf2][V]
    short8 aF[2][4], bv0[4], bv1[4];

    // window (H,V): 8 MFMA 32x32x16 (2 mf2-chains x 4 k)
#define MFMA_W(H, V, BV) do {                                                 \
        __builtin_amdgcn_s_setprio(1);                                        \
        _Pragma("unroll")                                                     \
        for (int k = 0; k < 4; ++k)                                           \
            _Pragma("unroll")                                                 \
            for (int mf2 = 0; mf2 < 2; ++mf2)                                 \
                acc[(H)*2 + mf2][V] =                                         \
                    __builtin_amdgcn_mfma_f32_32x32x16_bf16(                  \
                        aF[mf2][k], BV[k], acc[(H)*2 + mf2][V], 0, 0, 0);     \
        __builtin_amdgcn_s_setprio(0);                                        \
    } while (0)

#define TILE(T, LAC, LBC, LAN, LBN, S1F, S23F, RN, VC) do {                   \
        __builtin_amdgcn_s_barrier();                                         \
        MFMA_W(0, 0, bv0);                                                    \
        LDB_V(bv1, 1, LBC);                                                   \
        if (S1F) { STAGE_B(1, (T) + 1, LBN); STAGE_A(1, (T) + 1, LAN); }      \
        __builtin_amdgcn_s_barrier();                                         \
        MFMA_W(0, 1, bv1);                                                    \
        LDA_HF(1, LAC);                                                       \
        if (S23F) STAGE_B(0, (T) + 2, LBC);                                   \
        __builtin_amdgcn_s_barrier();                                         \
        MFMA_W(1, 0, bv0);                                                    \
        if (S23F) STAGE_A(0, (T) + 2, LAC);                                   \
        asm volatile("s_waitcnt vmcnt(" VC ")" ::: "memory");                 \
        __builtin_amdgcn_s_barrier();                                         \
        MFMA_W(1, 1, bv1);                                                    \
        if (RN) { LDA_HF(0, LAN); LDB_V(bv0, 0, LBN); }                       \
    } while (0)

    // prologue: 12 gloads (tile0's 4 halves + tile1's B0/A0); vmcnt(4)
    // retires tile0's 8; publish; pre-read tile0's H0/bv0.
    STAGE_B(0, 0, LSB0); STAGE_A(0, 0, LSA0);
    STAGE_B(1, 0, LSB0); STAGE_A(1, 0, LSA0);
    STAGE_B(0, 1, LSB1); STAGE_A(0, 1, LSA1);
    asm volatile("s_waitcnt vmcnt(4)" ::: "memory");
    __builtin_amdgcn_s_barrier();
    LDA_HF(0, LSA0); LDB_V(bv0, 0, LSB0);

#pragma unroll 1
    for (int t = 0; t + 2 <= NT2 - 2; t += 2) {
        TILE(t,     LSA0, LSB0, LSA1, LSB1, 1, 1, 1, "4");
        TILE(t + 1, LSA1, LSB1, LSA0, LSB0, 1, 1, 1, "4");
    }
    TILE(NT2 - 2, LSA0, LSB0, LSA1, LSB1, 1, 0, 1, "0");
    TILE(NT2 - 1, LSA1, LSB1, LSA0, LSB0, 0, 0, 0, "0");

    // epilogue: 32x32 C/D: col=lane&31, row=(r&3)+8*(r>>2)+4*(lane>>5)
    const int rbase = 4 * (lane >> 5), fcol = lane & 31;
    if (NSPLIT == 1 || s == 0) {
#pragma unroll
        for (int H = 0; H < 2; ++H)
#pragma unroll
            for (int mf2 = 0; mf2 < 2; ++mf2)
#pragma unroll
                for (int V = 0; V < 2; ++V)
#pragma unroll
                    for (int r = 0; r < 16; ++r) {
                        int row = brow + H * 128 + wm * 64 + mf2 * 32
                                + (r & 3) + 8 * (r >> 2) + rbase;
                        int col = bcol + V * 128 + wn * 32 + fcol;
                        C[(size_t)row * OUTN + col] = acc[H * 2 + mf2][V][r];
                    }
    } else {
        unsigned short* Pb = P + (size_t)(s - 1) * BATCH * OUTN;
#pragma unroll
        for (int H = 0; H < 2; ++H)
#pragma unroll
            for (int mf2 = 0; mf2 < 2; ++mf2)
#pragma unroll
                for (int V = 0; V < 2; ++V)
#pragma unroll
                    for (int r = 0; r < 16; ++r) {
                        int row = brow + H * 128 + wm * 64 + mf2 * 32
                                + (r & 3) + 8 * (r >> 2) + rbase;
                        int col = bcol + V * 128 + wn * 32 + fcol;
                        Pb[(size_t)row * OUTN + col] = f2bf(acc[H * 2 + mf2][V][r]);
                    }
    }
}

// ---------- kernel 3: C += sum of np bf16 partials ----------

__global__ void reduce_kernel(float* __restrict__ C, const unsigned short* __restrict__ P,
                              int np) {
    int i = blockIdx.x * 256 + threadIdx.x;        // 524,288 threads x 8 f32
    size_t base = (size_t)i * 8;
    f32x4 c0 = *reinterpret_cast<f32x4*>(&C[base]);
    f32x4 c1 = *reinterpret_cast<f32x4*>(&C[base + 4]);
    for (int j = 0; j < np; ++j) {
        ushort8 p = *reinterpret_cast<const ushort8*>(&P[(size_t)j * BATCH * OUTN + base]);
#pragma unroll
        for (int e = 0; e < 4; ++e) c0[e] += bf2f(p[e]);
#pragma unroll
        for (int e = 0; e < 4; ++e) c1[e] += bf2f(p[4 + e]);
    }
    *reinterpret_cast<f32x4*>(&C[base])     = c0;
    *reinterpret_cast<f32x4*>(&C[base + 4]) = c1;
}

// ---------- launch ----------

extern "C" void kernel_launch(void* const* d_in, const int* in_sizes, int n_in,
                              void* d_out, int out_size, void* d_ws, size_t ws_size,
                              hipStream_t stream) {
    const float* x    = (const float*)d_in[0];
    const float* coef = (const float*)d_in[1];
    float* out = (float*)d_out;

    // ws: [A_shuf 64 MiB][B_shuf 16 MiB][bf16 partials 8 MiB x (NSPLIT-1)]
    unsigned short* ashuf = (unsigned short*)d_ws;
    unsigned short* bshuf = ashuf + (size_t)BATCH * KDIM;
    unsigned short* part  = bshuf + (size_t)OUTN * KDIM;
    const size_t base = (size_t)BATCH * KDIM * 2 + (size_t)OUTN * KDIM * 2;  // 80 MiB
    const size_t slab = (size_t)BATCH * OUTN * 2;                            // 8 MiB

    prep_kernel<<<5120, 256, 0, stream>>>(x, coef, ashuf, bshuf);

    if (ws_size >= base + 3 * slab) {
        gemm_bt<4><<<256, 512, 0, stream>>>(ashuf, bshuf, out, part);
        reduce_kernel<<<2048, 256, 0, stream>>>(out, part, 3);
    } else if (ws_size >= base + slab) {
        gemm_bt<2><<<128, 512, 0, stream>>>(ashuf, bshuf, out, part);
        reduce_kernel<<<2048, 256, 0, stream>>>(out, part, 1);
    } else {
        gemm_bt<1><<<64, 512, 0, stream>>>(ashuf, bshuf, out, nullptr);
    }
}

// Round 5
// 101.113 us; speedup vs baseline: 1.0234x; 1.0234x over previous
//
#include <hip/hip_runtime.h>
#include <stdint.h>
#include <stddef.h>

// Problem: out[b][o] = sum_{i,g} spline(x[b][i])[g] * coef[o][i][g]
//   x: (4096, 1024) f32; coef: (1024, 1024, 8) f32; out: (4096, 1024) f32
// == GEMM: A (4096 x 8192) * B^T (1024 x 8192), K = i*8+g.
//
// R5 = R0 (best measured, 57.2us) + B-BYPASS done with R0's wait slack.
// B fragments load global->VGPR at the exact window positions where R0
// issued B stage/reads (W3/W4, right after the MFMA that frees the regs);
// A keeps R0's LDS staging verbatim. All waits (explicit vmcnt(6) and
// compiler-inserted bv waits) have >=2-window slack -- R3's 1-window-slack
// vmcnt bug is what lost; the traffic cut (-64KB LDS reads, -32KB writes
// per tile) is preserved. 256x256 tile, 8 waves, 16x16x32, split-K=4.
// Windows per tile t (A bufs c=t%2, n):
//  W1: BAR; Q(0,0)[aF=H0,bv0]; stage A1(t+1)->n (2gl)
//  W2: BAR; Q(0,1)[aF,bv1];    read aF<-H1(t)@c
//  W3: BAR; Q(1,0)[aF,bv0];    stage A0(t+2)->c (2gl); load bv0(t+1) (4gl);
//      vmcnt(6) [6 newest = A0(t+2)+bv0(t+1); waits A1(t+1), 2 windows old]
//  W4: BAR(publish t+1); Q(1,1)[aF,bv1]; read aF<-H0(t+1)@n; load bv1(t+1)
// Compiler waits: bv0(t) @W1: 4 newer (bv1(t-1->t? no: W4(t-1) bv1(t) 4gl)
//   -> 2-window slack; bv1(t) @W2: 2 newer (A1(t+1)) -> 2-window slack. OK.
// LDS slot safety: A0@c last read W4(t-1) (lgkm-consumed by Q(0,0)@W1);
// re-staged W3(t): 2 barriers later. A1@n last read W2; re-staged W1(t+1)
// after 3 barriers. Same discipline as R0.

#define BATCH 4096
#define IN    1024
#define OUTN  1024
#define KDIM  (IN * 8)     // 8192
#define NTT   (KDIM / 64)  // 128 K-tiles of BK=64

typedef __attribute__((ext_vector_type(8)))  short          short8;
typedef __attribute__((ext_vector_type(8)))  unsigned short ushort8;
typedef __attribute__((ext_vector_type(4)))  float          f32x4;

// ---------- helpers ----------

__device__ __forceinline__ constexpr float Cf(int i) {
    constexpr double end  = 1.0 + 2.0 * 4.0 / 7.0;        // 1 + 8/7
    constexpr double step = (end - (-1.0)) / 11.0;
    return (float)(-1.0 + (double)i * step);
}

__device__ __forceinline__ unsigned short f2bf(float f) {
    unsigned int u = __builtin_bit_cast(unsigned int, f);
    u += 0x7fffu + ((u >> 16) & 1u);      // round-to-nearest-even
    return (unsigned short)(u >> 16);
}

__device__ __forceinline__ float bf2f(unsigned short u) {
    unsigned int v = (unsigned int)u << 16;
    return __builtin_bit_cast(float, v);
}

__device__ __forceinline__ ushort8 spline8(float xt) {
    float v[11];
#pragma unroll
    for (int j = 0; j < 11; ++j)
        v[j] = (xt >= Cf(j) && xt < Cf(j + 1)) ? 1.0f : 0.0f;
#pragma unroll
    for (int k = 1; k <= 3; ++k) {
#pragma unroll
        for (int j = 0; j < 11 - k; ++j) {
            float left  = (xt - Cf(j))         * (1.0f / (Cf(j + k)     - Cf(j)));
            float right = (Cf(j + k + 1) - xt) * (1.0f / (Cf(j + k + 1) - Cf(j + 1)));
            v[j] = left * v[j] + right * v[j + 1];
        }
    }
    ushort8 r;
#pragma unroll
    for (int g = 0; g < 8; ++g) r[g] = f2bf(v[g]);
    return r;
}

typedef const unsigned int __attribute__((address_space(1))) gu32;
typedef unsigned int       __attribute__((address_space(3))) lu32;

__device__ __forceinline__ void gload_lds16(const void* g, void* l) {
    __builtin_amdgcn_global_load_lds((gu32*)g, (lu32*)l, 16, 0, 0);
}

// ---------- kernel 1: fused prep -> A_shuf / B_shuf fragment images ----------
//
// 16x16x32 frag map: row = lane&15, k = kb*32 + (lane>>4)*8 + e.
// Image (ushort8 units): [rg=row>>4][kb=k>>5][lane][e].
// Element (row, i, g): kb = i>>2, lane = (i&3)*16 + (row&15), e = g.

__global__ void prep_kernel(const float* __restrict__ x, const float* __restrict__ coef,
                            unsigned short* __restrict__ A, unsigned short* __restrict__ B) {
    const int t = threadIdx.x;
    int blk = blockIdx.x;
    if (blk < 4096) {
        // basis: 256 bb x 16 bi blocks; row = b
        const int bb = blk >> 4, bi = blk & 15;
        const int b  = bb * 16 + (t & 15);
        const int i0 = bi * 64 + (t >> 4) * 4;
        f32x4 xv = *reinterpret_cast<const f32x4*>(&x[(size_t)b * IN + i0]);
        ushort8 r[4];
#pragma unroll
        for (int j = 0; j < 4; ++j) r[j] = spline8(tanhf(xv[j]));
        ushort8* out = reinterpret_cast<ushort8*>(A)
                     + ((size_t)(bb * 256 + bi * 16 + (t >> 4)) * 64) + (t & 15);
        out[0]  = r[0];
        out[16] = r[1];
        out[32] = r[2];
        out[48] = r[3];
    } else {
        // coef cvt: 64 ob x 16 ib blocks; row = o
        blk -= 4096;
        const int ob = blk >> 4, ib = blk & 15;
        const int oo = ob * 16 + (t & 15);
        const int i0 = ib * 64 + (t >> 4) * 4;
        const f32x4* cin = reinterpret_cast<const f32x4*>(coef);
        ushort8 r[4];
#pragma unroll
        for (int j = 0; j < 4; ++j) {
            f32x4 v0 = cin[((size_t)oo * IN + i0 + j) * 2];
            f32x4 v1 = cin[((size_t)oo * IN + i0 + j) * 2 + 1];
#pragma unroll
            for (int g = 0; g < 4; ++g) { r[j][g] = f2bf(v0[g]); r[j][4 + g] = f2bf(v1[g]); }
        }
        ushort8* out = reinterpret_cast<ushort8*>(B)
                     + ((size_t)(ob * 256 + ib * 16 + (t >> 4)) * 64) + (t & 15);
        out[0]  = r[0];
        out[16] = r[1];
        out[32] = r[2];
        out[48] = r[3];
    }
}

// ---------- kernel 2: 256x256 bf16 GEMM, A-in-LDS, B-in-regs ----------

#define LSA0 (&Ls[0][0])
#define LSA1 (&Ls[1][0])

template<int NSPLIT>
__global__ __launch_bounds__(512, 2) void gemm_bt(
        const unsigned short* __restrict__ Ashuf,  // [256 rg][256 kb][64][8]
        const unsigned short* __restrict__ Bshuf,  // [64 cg][256 kb][64][8]
        float* __restrict__ C,                     // [4096][1024]
        unsigned short* __restrict__ P) {          // bf16 partials (splits 1..)
    constexpr int NT2 = NTT / NSPLIT;              // K-tiles per block
    static_assert((NT2 & 1) == 0 && NT2 >= 8, "loop assumes even NT2 >= 8");
    __shared__ unsigned short Ls[2][16384];        // 2 x 32 KiB (A only)

    const int tid  = threadIdx.x;
    const int w    = tid >> 6;                     // 0..7
    const int lane = tid & 63;
    const int wm   = w >> 2, wn = w & 3;
    const int kkw  = w & 1, wh = w >> 1;           // staging roles
    const int lane8 = lane * 8;

    const int bid  = blockIdx.x;
    const int s    = bid & (NSPLIT - 1);
    const int tile = bid / NSPLIT;                 // 0..63
    const int mb16 = (tile >> 2) * 16;             // A rg base
    const int nb16 = (tile & 3) * 16;              // B cg base
    const int T0   = s * NT2;
    const int brow = mb16 * 16, bcol = nb16 * 16;

    // A half-stage: 16 KiB, wave w covers rg=H*8+wh (and +4), kb-half kkw.
#define STAGE_A(H, T, LS) do {                                                \
        size_t _kq = ((size_t)(2 * (T0 + (T)) + kkw)) * 512 + lane8;          \
        const unsigned short* _g = Ashuf + ((size_t)(mb16 + (H)*8 + wh) << 17) + _kq; \
        unsigned short* _l = (LS) + (((H)*16 + w) << 9);                      \
        gload_lds16(_g, _l);                                                  \
        gload_lds16(_g + ((size_t)4 << 17), _l + (8 << 9));                   \
    } while (0)

#define LDA_F(DST, H, LS) do {                                                \
        _Pragma("unroll")                                                     \
        for (int mf = 0; mf < 4; ++mf)                                        \
            _Pragma("unroll")                                                 \
            for (int kk = 0; kk < 2; ++kk)                                    \
                DST[mf][kk] = *reinterpret_cast<const short8*>(               \
                    (LS) + (((((H)*8 + wm*4 + mf) * 2) + kk) << 9) + lane8);  \
    } while (0)

    // B direct load: V-half (4 x global_load_dwordx4, 1 KiB/wave, coalesced)
#define LOADB(DST, T, V) do {                                                 \
        size_t _kb = (size_t)(2 * (T0 + (T))) * 512 + lane8;                  \
        _Pragma("unroll")                                                     \
        for (int nf = 0; nf < 2; ++nf)                                        \
            _Pragma("unroll")                                                 \
            for (int kk = 0; kk < 2; ++kk)                                    \
                DST[nf][kk] = *reinterpret_cast<const short8*>(               \
                    Bshuf + (((size_t)(nb16 + (V)*8 + wn*2 + nf)) << 17)      \
                          + _kb + (size_t)kk * 512);                          \
    } while (0)

    f32x4 acc[8][4] = {};                          // [H*4+mf][V*2+nf]
    short8 aF[4][2], bv0[2][2], bv1[2][2];

#define MFMA_Q(H, V, AF, BV) do {                                             \
        __builtin_amdgcn_s_setprio(1);                                        \
        _Pragma("unroll")                                                     \
        for (int kk = 0; kk < 2; ++kk)                                        \
            _Pragma("unroll")                                                 \
            for (int mf = 0; mf < 4; ++mf)                                    \
                _Pragma("unroll")                                             \
                for (int nf = 0; nf < 2; ++nf)                                \
                    acc[(H)*4 + mf][(V)*2 + nf] =                             \
                        __builtin_amdgcn_mfma_f32_16x16x32_bf16(              \
                            AF[mf][kk], BV[nf][kk],                           \
                            acc[(H)*4 + mf][(V)*2 + nf], 0, 0, 0);            \
        __builtin_amdgcn_s_setprio(0);                                        \
    } while (0)

#define TILE(T, LAC, LAN, S1F, S23F, BFLAG, RN, VC) do {                      \
        __builtin_amdgcn_s_barrier();                                         \
        MFMA_Q(0, 0, aF, bv0);                                                \
        if (S1F) STAGE_A(1, (T) + 1, LAN);                                    \
        __builtin_amdgcn_s_barrier();                                         \
        MFMA_Q(0, 1, aF, bv1);                                                \
        LDA_F(aF, 1, LAC);                                                    \
        __builtin_amdgcn_s_barrier();                                         \
        MFMA_Q(1, 0, aF, bv0);                                                \
        if (S23F) STAGE_A(0, (T) + 2, LAC);                                   \
        if (BFLAG) LOADB(bv0, (T) + 1, 0);                                    \
        asm volatile("s_waitcnt vmcnt(" VC ")" ::: "memory");                 \
        __builtin_amdgcn_s_barrier();                                         \
        MFMA_Q(1, 1, aF, bv1);                                                \
        if (RN) LDA_F(aF, 0, LAN);                                            \
        if (BFLAG) LOADB(bv1, (T) + 1, 1);                                    \
    } while (0)

    // prologue: A(0) both halves -> b0 (4gl), A0(1) -> b1 (2gl),
    // bv0(0)+bv1(0) (8gl) = 14 events; vmcnt(10) retires A(0)'s 4;
    // publish; pre-read tile0's H0. A1(1) staged at W1(0) (steady state).
    STAGE_A(0, 0, LSA0); STAGE_A(1, 0, LSA0);
    STAGE_A(0, 1, LSA1);
    LOADB(bv0, 0, 0); LOADB(bv1, 0, 1);
    asm volatile("s_waitcnt vmcnt(10)" ::: "memory");
    __builtin_amdgcn_s_barrier();
    LDA_F(aF, 0, LSA0);

#pragma unroll 1
    for (int t = 0; t + 2 <= NT2 - 2; t += 2) {
        TILE(t,     LSA0, LSA1, 1, 1, 1, 1, "6");
        TILE(t + 1, LSA1, LSA0, 1, 1, 1, 1, "6");
    }
    // tail: NT2-2 stages A1(NT2-1) only (no t+2), still loads bv(NT2-1);
    // vmcnt(4) keeps bv0(NT2-1)'s 4 in flight, retires A1(NT2-1).
    TILE(NT2 - 2, LSA0, LSA1, 1, 0, 1, 1, "4");
    TILE(NT2 - 1, LSA1, LSA0, 0, 0, 0, 0, "0");

    // epilogue: C/D layout col=lane&15, row=(lane>>4)*4+reg (m89-verified)
    // s==0 -> f32 to C; s>0 -> bf16 partial slab (reduce kernel sums).
    const int q4 = (lane >> 4) * 4, frow = lane & 15;
    if (NSPLIT == 1 || s == 0) {
#pragma unroll
        for (int H = 0; H < 2; ++H)
#pragma unroll
            for (int mf = 0; mf < 4; ++mf)
#pragma unroll
                for (int V = 0; V < 2; ++V)
#pragma unroll
                    for (int nf = 0; nf < 2; ++nf)
#pragma unroll
                        for (int r = 0; r < 4; ++r) {
                            int row = brow + H * 128 + wm * 64 + mf * 16 + q4 + r;
                            int col = bcol + V * 128 + wn * 32 + nf * 16 + frow;
                            C[(size_t)row * OUTN + col] = acc[H * 4 + mf][V * 2 + nf][r];
                        }
    } else {
        unsigned short* Pb = P + (size_t)(s - 1) * BATCH * OUTN;
#pragma unroll
        for (int H = 0; H < 2; ++H)
#pragma unroll
            for (int mf = 0; mf < 4; ++mf)
#pragma unroll
                for (int V = 0; V < 2; ++V)
#pragma unroll
                    for (int nf = 0; nf < 2; ++nf)
#pragma unroll
                        for (int r = 0; r < 4; ++r) {
                            int row = brow + H * 128 + wm * 64 + mf * 16 + q4 + r;
                            int col = bcol + V * 128 + wn * 32 + nf * 16 + frow;
                            Pb[(size_t)row * OUTN + col] = f2bf(acc[H * 4 + mf][V * 2 + nf][r]);
                        }
    }
}

// ---------- kernel 3: C += sum of np bf16 partials ----------

__global__ void reduce_kernel(float* __restrict__ C, const unsigned short* __restrict__ P,
                              int np) {
    int i = blockIdx.x * 256 + threadIdx.x;        // 524,288 threads x 8 f32
    size_t base = (size_t)i * 8;
    f32x4 c0 = *reinterpret_cast<f32x4*>(&C[base]);
    f32x4 c1 = *reinterpret_cast<f32x4*>(&C[base + 4]);
    for (int j = 0; j < np; ++j) {
        ushort8 p = *reinterpret_cast<const ushort8*>(&P[(size_t)j * BATCH * OUTN + base]);
#pragma unroll
        for (int e = 0; e < 4; ++e) c0[e] += bf2f(p[e]);
#pragma unroll
        for (int e = 0; e < 4; ++e) c1[e] += bf2f(p[4 + e]);
    }
    *reinterpret_cast<f32x4*>(&C[base])     = c0;
    *reinterpret_cast<f32x4*>(&C[base + 4]) = c1;
}

// ---------- launch ----------

extern "C" void kernel_launch(void* const* d_in, const int* in_sizes, int n_in,
                              void* d_out, int out_size, void* d_ws, size_t ws_size,
                              hipStream_t stream) {
    const float* x    = (const float*)d_in[0];
    const float* coef = (const float*)d_in[1];
    float* out = (float*)d_out;

    // ws: [A_shuf 64 MiB][B_shuf 16 MiB][bf16 partials 8 MiB x (NSPLIT-1)]
    unsigned short* ashuf = (unsigned short*)d_ws;
    unsigned short* bshuf = ashuf + (size_t)BATCH * KDIM;
    unsigned short* part  = bshuf + (size_t)OUTN * KDIM;
    const size_t base = (size_t)BATCH * KDIM * 2 + (size_t)OUTN * KDIM * 2;  // 80 MiB
    const size_t slab = (size_t)BATCH * OUTN * 2;                            // 8 MiB

    prep_kernel<<<5120, 256, 0, stream>>>(x, coef, ashuf, bshuf);

    if (ws_size >= base + 3 * slab) {
        gemm_bt<4><<<256, 512, 0, stream>>>(ashuf, bshuf, out, part);
        reduce_kernel<<<2048, 256, 0, stream>>>(out, part, 3);
    } else if (ws_size >= base + slab) {
        gemm_bt<2><<<128, 512, 0, stream>>>(ashuf, bshuf, out, part);
        reduce_kernel<<<2048, 256, 0, stream>>>(out, part, 1);
    } else {
        gemm_bt<1><<<64, 512, 0, stream>>>(ashuf, bshuf, out, nullptr);
    }
}

// Round 6
// 98.416 us; speedup vs baseline: 1.0514x; 1.0274x over previous
//
#include <hip/hip_runtime.h>
#include <stdint.h>
#include <stddef.h>

// Problem: out[b][o] = sum_{i,g} spline(x[b][i])[g] * coef[o][i][g]
//   x: (4096, 1024) f32; coef: (1024, 1024, 8) f32; out: (4096, 1024) f32
// == GEMM: A (4096 x 8192) * B^T (1024 x 8192), K = i*8+g.
//
// R6 = R0's staging/vmcnt schedule + m201's 8-phase barrier skeleton.
// Per phase: {pre-region: ds_reads for THIS phase + stage gloads} BAR
// {setprio 16xMFMA setprio} BAR. Reads complete while waves collect at the
// barrier; LDS unit gets batched back-to-back reads (m201 measured ~3300
// cyc/tile on identical geometry vs R0's 4290). Staging (identical to R0):
//  P1-pre: read aF(H0,t),bv0(t)<-cur; stage B1,A1(t+1)->next
//  P2-pre: read bv1(t)<-cur;          stage B0(t+2)->cur
//  P3-pre: read aF(H1,t)<-cur;        stage A0(t+2)->cur
//  P4-pre: vmcnt(4)
// vmcnt(4)@t.P4 retire audit (per-wave, oldest first): B0(t+1)2 A0(t+1)2
// [from t-1.P2/P3], B1A1(t+1)4 [t.P1], B0(t+2)2 [t.P2], A0(t+2)2 [t.P3]
// = 12 outstanding -> vmcnt(4) retires the 8 oldest = ALL of tile t+1's
// halves, before t+1.P1's reads (one barrier later). Slot-reuse safety:
// every stage lands >=2 barriers after the staged slot's last read was
// lgkm-consumed (audited per-slot in R0, unchanged).
// 256x256 tile, 8 waves, 16x16x32, split-K=4; s=0 -> f32 C, s>0 -> bf16
// partials; reduce kernel sums.

#define BATCH 4096
#define IN    1024
#define OUTN  1024
#define KDIM  (IN * 8)     // 8192
#define NTT   (KDIM / 64)  // 128 K-tiles of BK=64

typedef __attribute__((ext_vector_type(8)))  short          short8;
typedef __attribute__((ext_vector_type(8)))  unsigned short ushort8;
typedef __attribute__((ext_vector_type(4)))  float          f32x4;

// ---------- helpers ----------

__device__ __forceinline__ constexpr float Cf(int i) {
    constexpr double end  = 1.0 + 2.0 * 4.0 / 7.0;        // 1 + 8/7
    constexpr double step = (end - (-1.0)) / 11.0;
    return (float)(-1.0 + (double)i * step);
}

__device__ __forceinline__ unsigned short f2bf(float f) {
    unsigned int u = __builtin_bit_cast(unsigned int, f);
    u += 0x7fffu + ((u >> 16) & 1u);      // round-to-nearest-even
    return (unsigned short)(u >> 16);
}

__device__ __forceinline__ float bf2f(unsigned short u) {
    unsigned int v = (unsigned int)u << 16;
    return __builtin_bit_cast(float, v);
}

__device__ __forceinline__ ushort8 spline8(float xt) {
    float v[11];
#pragma unroll
    for (int j = 0; j < 11; ++j)
        v[j] = (xt >= Cf(j) && xt < Cf(j + 1)) ? 1.0f : 0.0f;
#pragma unroll
    for (int k = 1; k <= 3; ++k) {
#pragma unroll
        for (int j = 0; j < 11 - k; ++j) {
            float left  = (xt - Cf(j))         * (1.0f / (Cf(j + k)     - Cf(j)));
            float right = (Cf(j + k + 1) - xt) * (1.0f / (Cf(j + k + 1) - Cf(j + 1)));
            v[j] = left * v[j] + right * v[j + 1];
        }
    }
    ushort8 r;
#pragma unroll
    for (int g = 0; g < 8; ++g) r[g] = f2bf(v[g]);
    return r;
}

typedef const unsigned int __attribute__((address_space(1))) gu32;
typedef unsigned int       __attribute__((address_space(3))) lu32;

__device__ __forceinline__ void gload_lds16(const void* g, void* l) {
    __builtin_amdgcn_global_load_lds((gu32*)g, (lu32*)l, 16, 0, 0);
}

// ---------- kernel 1: fused prep -> A_shuf / B_shuf fragment images ----------
//
// 16x16x32 frag map: row = lane&15, k = kb*32 + (lane>>4)*8 + e.
// Image (ushort8 units): [rg=row>>4][kb=k>>5][lane][e].
// Element (row, i, g): kb = i>>2, lane = (i&3)*16 + (row&15), e = g.

__global__ void prep_kernel(const float* __restrict__ x, const float* __restrict__ coef,
                            unsigned short* __restrict__ A, unsigned short* __restrict__ B) {
    const int t = threadIdx.x;
    int blk = blockIdx.x;
    if (blk < 4096) {
        // basis: 256 bb x 16 bi blocks; row = b
        const int bb = blk >> 4, bi = blk & 15;
        const int b  = bb * 16 + (t & 15);
        const int i0 = bi * 64 + (t >> 4) * 4;
        f32x4 xv = *reinterpret_cast<const f32x4*>(&x[(size_t)b * IN + i0]);
        ushort8 r[4];
#pragma unroll
        for (int j = 0; j < 4; ++j) r[j] = spline8(tanhf(xv[j]));
        ushort8* out = reinterpret_cast<ushort8*>(A)
                     + ((size_t)(bb * 256 + bi * 16 + (t >> 4)) * 64) + (t & 15);
        out[0]  = r[0];
        out[16] = r[1];
        out[32] = r[2];
        out[48] = r[3];
    } else {
        // coef cvt: 64 ob x 16 ib blocks; row = o
        blk -= 4096;
        const int ob = blk >> 4, ib = blk & 15;
        const int oo = ob * 16 + (t & 15);
        const int i0 = ib * 64 + (t >> 4) * 4;
        const f32x4* cin = reinterpret_cast<const f32x4*>(coef);
        ushort8 r[4];
#pragma unroll
        for (int j = 0; j < 4; ++j) {
            f32x4 v0 = cin[((size_t)oo * IN + i0 + j) * 2];
            f32x4 v1 = cin[((size_t)oo * IN + i0 + j) * 2 + 1];
#pragma unroll
            for (int g = 0; g < 4; ++g) { r[j][g] = f2bf(v0[g]); r[j][4 + g] = f2bf(v1[g]); }
        }
        ushort8* out = reinterpret_cast<ushort8*>(B)
                     + ((size_t)(ob * 256 + ib * 16 + (t >> 4)) * 64) + (t & 15);
        out[0]  = r[0];
        out[16] = r[1];
        out[32] = r[2];
        out[48] = r[3];
    }
}

// ---------- kernel 2: 256x256 bf16 GEMM, 8-phase (m201 skeleton) ----------

#define LSA0 (&Ls[0][0])
#define LSB0 (&Ls[0][16384])
#define LSA1 (&Ls[1][0])
#define LSB1 (&Ls[1][16384])

template<int NSPLIT>
__global__ __launch_bounds__(512, 2) void gemm_bt(
        const unsigned short* __restrict__ Ashuf,  // [256 rg][256 kb][64][8]
        const unsigned short* __restrict__ Bshuf,  // [64 cg][256 kb][64][8]
        float* __restrict__ C,                     // [4096][1024]
        unsigned short* __restrict__ P) {          // bf16 partials (splits 1..)
    constexpr int NT2 = NTT / NSPLIT;              // K-tiles per block
    static_assert((NT2 & 1) == 0 && NT2 >= 8, "loop assumes even NT2 >= 8");
    __shared__ unsigned short Ls[2][32768];        // 128 KiB

    const int tid  = threadIdx.x;
    const int w    = tid >> 6;                     // 0..7
    const int lane = tid & 63;
    const int wm   = w >> 2, wn = w & 3;
    const int kkw  = w & 1, wh = w >> 1;           // staging roles
    const int lane8 = lane * 8;

    const int bid  = blockIdx.x;
    const int s    = bid & (NSPLIT - 1);
    const int tile = bid / NSPLIT;                 // 0..63
    const int mb16 = (tile >> 2) * 16;             // A rg base
    const int nb16 = (tile & 3) * 16;              // B cg base
    const int T0   = s * NT2;
    const int brow = mb16 * 16, bcol = nb16 * 16;

#define STAGE_OP(BASE, NB16, H, T, LS) do {                                   \
        size_t _kq = ((size_t)(2 * (T0 + (T)) + kkw)) * 512 + lane8;          \
        const unsigned short* _g = (BASE) + ((size_t)((NB16) + (H)*8 + wh) << 17) + _kq; \
        unsigned short* _l = (LS) + (((H)*16 + w) << 9);                      \
        gload_lds16(_g, _l);                                                  \
        gload_lds16(_g + ((size_t)4 << 17), _l + (8 << 9));                   \
    } while (0)
#define STAGE_A(H, T, LS) STAGE_OP(Ashuf, mb16, H, T, LS)
#define STAGE_B(H, T, LS) STAGE_OP(Bshuf, nb16, H, T, LS)

#define LDA_F(DST, H, LS) do {                                                \
        _Pragma("unroll")                                                     \
        for (int mf = 0; mf < 4; ++mf)                                        \
            _Pragma("unroll")                                                 \
            for (int kk = 0; kk < 2; ++kk)                                    \
                DST[mf][kk] = *reinterpret_cast<const short8*>(               \
                    (LS) + (((((H)*8 + wm*4 + mf) * 2) + kk) << 9) + lane8);  \
    } while (0)
#define LDB_F(DST, V, LS) do {                                                \
        _Pragma("unroll")                                                     \
        for (int nf = 0; nf < 2; ++nf)                                        \
            _Pragma("unroll")                                                 \
            for (int kk = 0; kk < 2; ++kk)                                    \
                DST[nf][kk] = *reinterpret_cast<const short8*>(               \
                    (LS) + (((((V)*8 + wn*2 + nf) * 2) + kk) << 9) + lane8);  \
    } while (0)

    f32x4 acc[8][4] = {};                          // [H*4+mf][V*2+nf]
    short8 aF[4][2], bv0[2][2], bv1[2][2];

#define MFMA_Q(H, V, AF, BV) do {                                             \
        __builtin_amdgcn_s_setprio(1);                                        \
        _Pragma("unroll")                                                     \
        for (int kk = 0; kk < 2; ++kk)                                        \
            _Pragma("unroll")                                                 \
            for (int mf = 0; mf < 4; ++mf)                                    \
                _Pragma("unroll")                                             \
                for (int nf = 0; nf < 2; ++nf)                                \
                    acc[(H)*4 + mf][(V)*2 + nf] =                             \
                        __builtin_amdgcn_mfma_f32_16x16x32_bf16(              \
                            AF[mf][kk], BV[nf][kk],                           \
                            acc[(H)*4 + mf][(V)*2 + nf], 0, 0, 0);            \
        __builtin_amdgcn_s_setprio(0);                                        \
    } while (0)

    // m201 skeleton: per phase {pre-region reads+stages} BAR {MFMA} BAR.
#define TILE(T, LAC, LBC, LAN, LBN, S1F, S23F, VC) do {                       \
        /* P1 */                                                              \
        LDA_F(aF, 0, LAC); LDB_F(bv0, 0, LBC);                                \
        if (S1F) { STAGE_B(1, (T) + 1, LBN); STAGE_A(1, (T) + 1, LAN); }      \
        __builtin_amdgcn_s_barrier();                                         \
        MFMA_Q(0, 0, aF, bv0);                                                \
        __builtin_amdgcn_s_barrier();                                         \
        /* P2 */                                                              \
        LDB_F(bv1, 1, LBC);                                                   \
        if (S23F) STAGE_B(0, (T) + 2, LBC);                                   \
        __builtin_amdgcn_s_barrier();                                         \
        MFMA_Q(0, 1, aF, bv1);                                                \
        __builtin_amdgcn_s_barrier();                                         \
        /* P3 */                                                              \
        LDA_F(aF, 1, LAC);                                                    \
        if (S23F) STAGE_A(0, (T) + 2, LAC);                                   \
        __builtin_amdgcn_s_barrier();                                         \
        MFMA_Q(1, 0, aF, bv0);                                                \
        __builtin_amdgcn_s_barrier();                                         \
        /* P4 */                                                              \
        asm volatile("s_waitcnt vmcnt(" VC ")" ::: "memory");                 \
        __builtin_amdgcn_s_barrier();                                         \
        MFMA_Q(1, 1, aF, bv1);                                                \
        __builtin_amdgcn_s_barrier();                                         \
    } while (0)

    // prologue: stage tile0's 4 halves (8 gl) + B0,A0(1)->buf1 (4 gl);
    // vmcnt(4) retires tile0's 8; BAR publishes. TILE(0).P1 then reads
    // tile0 and stages B1,A1(1) -- steady-state pattern from the start.
    STAGE_B(0, 0, LSB0); STAGE_A(0, 0, LSA0);
    STAGE_B(1, 0, LSB0); STAGE_A(1, 0, LSA0);
    STAGE_B(0, 1, LSB1); STAGE_A(0, 1, LSA1);
    asm volatile("s_waitcnt vmcnt(4)" ::: "memory");
    __builtin_amdgcn_s_barrier();

#pragma unroll 1
    for (int t = 0; t + 2 <= NT2 - 2; t += 2) {
        TILE(t,     LSA0, LSB0, LSA1, LSB1, 1, 1, "4");
        TILE(t + 1, LSA1, LSB1, LSA0, LSB0, 1, 1, "4");
    }
    // tail: NT2-2 stages B1,A1(NT2-1) only; vmcnt(0) at its P4 retires all
    // of tile NT2-1 (8 outstanding) before its reads. NT2-1: no stages.
    TILE(NT2 - 2, LSA0, LSB0, LSA1, LSB1, 1, 0, "0");
    TILE(NT2 - 1, LSA1, LSB1, LSA0, LSB0, 0, 0, "0");

    // epilogue: C/D layout col=lane&15, row=(lane>>4)*4+reg (m89-verified)
    // s==0 -> f32 to C; s>0 -> bf16 partial slab (reduce kernel sums).
    const int q4 = (lane >> 4) * 4, frow = lane & 15;
    if (NSPLIT == 1 || s == 0) {
#pragma unroll
        for (int H = 0; H < 2; ++H)
#pragma unroll
            for (int mf = 0; mf < 4; ++mf)
#pragma unroll
                for (int V = 0; V < 2; ++V)
#pragma unroll
                    for (int nf = 0; nf < 2; ++nf)
#pragma unroll
                        for (int r = 0; r < 4; ++r) {
                            int row = brow + H * 128 + wm * 64 + mf * 16 + q4 + r;
                            int col = bcol + V * 128 + wn * 32 + nf * 16 + frow;
                            C[(size_t)row * OUTN + col] = acc[H * 4 + mf][V * 2 + nf][r];
                        }
    } else {
        unsigned short* Pb = P + (size_t)(s - 1) * BATCH * OUTN;
#pragma unroll
        for (int H = 0; H < 2; ++H)
#pragma unroll
            for (int mf = 0; mf < 4; ++mf)
#pragma unroll
                for (int V = 0; V < 2; ++V)
#pragma unroll
                    for (int nf = 0; nf < 2; ++nf)
#pragma unroll
                        for (int r = 0; r < 4; ++r) {
                            int row = brow + H * 128 + wm * 64 + mf * 16 + q4 + r;
                            int col = bcol + V * 128 + wn * 32 + nf * 16 + frow;
                            Pb[(size_t)row * OUTN + col] = f2bf(acc[H * 4 + mf][V * 2 + nf][r]);
                        }
    }
}

// ---------- kernel 3: C += sum of np bf16 partials ----------

__global__ void reduce_kernel(float* __restrict__ C, const unsigned short* __restrict__ P,
                              int np) {
    int i = blockIdx.x * 256 + threadIdx.x;        // 524,288 threads x 8 f32
    size_t base = (size_t)i * 8;
    f32x4 c0 = *reinterpret_cast<f32x4*>(&C[base]);
    f32x4 c1 = *reinterpret_cast<f32x4*>(&C[base + 4]);
    for (int j = 0; j < np; ++j) {
        ushort8 p = *reinterpret_cast<const ushort8*>(&P[(size_t)j * BATCH * OUTN + base]);
#pragma unroll
        for (int e = 0; e < 4; ++e) c0[e] += bf2f(p[e]);
#pragma unroll
        for (int e = 0; e < 4; ++e) c1[e] += bf2f(p[4 + e]);
    }
    *reinterpret_cast<f32x4*>(&C[base])     = c0;
    *reinterpret_cast<f32x4*>(&C[base + 4]) = c1;
}

// ---------- launch ----------

extern "C" void kernel_launch(void* const* d_in, const int* in_sizes, int n_in,
                              void* d_out, int out_size, void* d_ws, size_t ws_size,
                              hipStream_t stream) {
    const float* x    = (const float*)d_in[0];
    const float* coef = (const float*)d_in[1];
    float* out = (float*)d_out;

    // ws: [A_shuf 64 MiB][B_shuf 16 MiB][bf16 partials 8 MiB x (NSPLIT-1)]
    unsigned short* ashuf = (unsigned short*)d_ws;
    unsigned short* bshuf = ashuf + (size_t)BATCH * KDIM;
    unsigned short* part  = bshuf + (size_t)OUTN * KDIM;
    const size_t base = (size_t)BATCH * KDIM * 2 + (size_t)OUTN * KDIM * 2;  // 80 MiB
    const size_t slab = (size_t)BATCH * OUTN * 2;                            // 8 MiB

    prep_kernel<<<5120, 256, 0, stream>>>(x, coef, ashuf, bshuf);

    if (ws_size >= base + 3 * slab) {
        gemm_bt<4><<<256, 512, 0, stream>>>(ashuf, bshuf, out, part);
        reduce_kernel<<<2048, 256, 0, stream>>>(out, part, 3);
    } else if (ws_size >= base + slab) {
        gemm_bt<2><<<128, 512, 0, stream>>>(ashuf, bshuf, out, part);
        reduce_kernel<<<2048, 256, 0, stream>>>(out, part, 1);
    } else {
        gemm_bt<1><<<64, 512, 0, stream>>>(ashuf, bshuf, out, nullptr);
    }
}

// Round 7
// 96.529 us; speedup vs baseline: 1.0720x; 1.0196x over previous
//
#include <hip/hip_runtime.h>
#include <stdint.h>
#include <stddef.h>

// Problem: out[b][o] = sum_{i,g} spline(x[b][i])[g] * coef[o][i][g]
//   x: (4096, 1024) f32; coef: (1024, 1024, 8) f32; out: (4096, 1024) f32
// == GEMM: A (4096 x 8192) * B^T (1024 x 8192), K = i*8+g.
//
// Both operands pre-shuffled into 16x16x32-MFMA fragment images (prep_kernel)
// so the GEMM stages whole 1KB fragments via global_load_lds and every
// ds_read is base+lane*16 (conflict-free). 256x256 tile, 8 waves, split-K=4.
// Schedule: 4 windows/K-tile, SOFTWARE-PIPELINED READS: every MFMA cluster's
// operands were read >=1 window earlier; reads TRAIL the MFMA in each window
// so LDS-unit busy overlaps matrix-pipe busy. Counted vmcnt(4), setprio.
// Split s=0 writes C f32; s>0 write bf16 partials; reduce kernel sums.
//
// R7 NOTE: this is the R0 optimum restored verbatim. Probes R1-R6 (read
// interleave, 2-block occupancy, B-in-regs x2, 32x32x16 shape, m201 8-phase
// skeleton) all regressed by +2 to +8 us; R0's trailing-read 4-window
// structure is the best measured point of this family (gemm 57.2 us,
// ~65% LDS-pipe utilization, which bounds this tile geometry).

#define BATCH 4096
#define IN    1024
#define OUTN  1024
#define KDIM  (IN * 8)     // 8192
#define NTT   (KDIM / 64)  // 128 K-tiles of BK=64

typedef __attribute__((ext_vector_type(8)))  short          short8;
typedef __attribute__((ext_vector_type(8)))  unsigned short ushort8;
typedef __attribute__((ext_vector_type(4)))  float          f32x4;

// ---------- helpers ----------

__device__ __forceinline__ constexpr float Cf(int i) {
    constexpr double end  = 1.0 + 2.0 * 4.0 / 7.0;        // 1 + 8/7
    constexpr double step = (end - (-1.0)) / 11.0;
    return (float)(-1.0 + (double)i * step);
}

__device__ __forceinline__ unsigned short f2bf(float f) {
    unsigned int u = __builtin_bit_cast(unsigned int, f);
    u += 0x7fffu + ((u >> 16) & 1u);      // round-to-nearest-even
    return (unsigned short)(u >> 16);
}

__device__ __forceinline__ float bf2f(unsigned short u) {
    unsigned int v = (unsigned int)u << 16;
    return __builtin_bit_cast(float, v);
}

__device__ __forceinline__ ushort8 spline8(float xt) {
    float v[11];
#pragma unroll
    for (int j = 0; j < 11; ++j)
        v[j] = (xt >= Cf(j) && xt < Cf(j + 1)) ? 1.0f : 0.0f;
#pragma unroll
    for (int k = 1; k <= 3; ++k) {
#pragma unroll
        for (int j = 0; j < 11 - k; ++j) {
            float left  = (xt - Cf(j))         * (1.0f / (Cf(j + k)     - Cf(j)));
            float right = (Cf(j + k + 1) - xt) * (1.0f / (Cf(j + k + 1) - Cf(j + 1)));
            v[j] = left * v[j] + right * v[j + 1];
        }
    }
    ushort8 r;
#pragma unroll
    for (int g = 0; g < 8; ++g) r[g] = f2bf(v[g]);
    return r;
}

typedef const unsigned int __attribute__((address_space(1))) gu32;
typedef unsigned int       __attribute__((address_space(3))) lu32;

__device__ __forceinline__ void gload_lds16(const void* g, void* l) {
    __builtin_amdgcn_global_load_lds((gu32*)g, (lu32*)l, 16, 0, 0);
}

// ---------- kernel 1: fused prep -> A_shuf / B_shuf fragment images ----------
//
// 16x16x32 frag map: row = lane&15, k = kb*32 + (lane>>4)*8 + e.
// Image (ushort8 units): [rg=row>>4][kb=k>>5][lane][e].
// Element (row, i, g): kb = i>>2, lane = (i&3)*16 + (row&15), e = g.

__global__ void prep_kernel(const float* __restrict__ x, const float* __restrict__ coef,
                            unsigned short* __restrict__ A, unsigned short* __restrict__ B) {
    const int t = threadIdx.x;
    int blk = blockIdx.x;
    if (blk < 4096) {
        // basis: 256 bb x 16 bi blocks; row = b
        const int bb = blk >> 4, bi = blk & 15;
        const int b  = bb * 16 + (t & 15);
        const int i0 = bi * 64 + (t >> 4) * 4;
        f32x4 xv = *reinterpret_cast<const f32x4*>(&x[(size_t)b * IN + i0]);
        ushort8 r[4];
#pragma unroll
        for (int j = 0; j < 4; ++j) r[j] = spline8(tanhf(xv[j]));
        ushort8* out = reinterpret_cast<ushort8*>(A)
                     + ((size_t)(bb * 256 + bi * 16 + (t >> 4)) * 64) + (t & 15);
        out[0]  = r[0];
        out[16] = r[1];
        out[32] = r[2];
        out[48] = r[3];
    } else {
        // coef cvt: 64 ob x 16 ib blocks; row = o
        blk -= 4096;
        const int ob = blk >> 4, ib = blk & 15;
        const int oo = ob * 16 + (t & 15);
        const int i0 = ib * 64 + (t >> 4) * 4;
        const f32x4* cin = reinterpret_cast<const f32x4*>(coef);
        ushort8 r[4];
#pragma unroll
        for (int j = 0; j < 4; ++j) {
            f32x4 v0 = cin[((size_t)oo * IN + i0 + j) * 2];
            f32x4 v1 = cin[((size_t)oo * IN + i0 + j) * 2 + 1];
#pragma unroll
            for (int g = 0; g < 4; ++g) { r[j][g] = f2bf(v0[g]); r[j][4 + g] = f2bf(v1[g]); }
        }
        ushort8* out = reinterpret_cast<ushort8*>(B)
                     + ((size_t)(ob * 256 + ib * 16 + (t >> 4)) * 64) + (t & 15);
        out[0]  = r[0];
        out[16] = r[1];
        out[32] = r[2];
        out[48] = r[3];
    }
}

// ---------- kernel 2: 256x256 bf16 GEMM, pipelined 4 windows/K-tile ----------
//
// 8 waves (wm=w>>2, wn=w&3), per-wave output 128x64 interleaved H/V.
// Windows per tile t (buf c = t%2, n = other); every window: BAR, MFMA with
// PRE-READ operands, then trailing reads/stages (overlap MFMA execution):
//  W1: BAR; Q(0,0)[aF=A0(t),bv0(t): read W4(t-1)]; read bv1(t); stage B1,A1(t+1)->n
//  W2: BAR; Q(0,1)[aF,bv1]; read A1(t)->aF; stage B0(t+2)->c
//  W3: BAR; Q(1,0)[aF=A1,bv0]; stage A0(t+2)->c; vmcnt(4)
//  W4: BAR(publish t+1); Q(1,1)[aF,bv1]; read A0(t+1)->aF, bv0(t+1) from n
// Stage-safety: every LDS slot's last read is lgkm-consumed (by an MFMA in an
// earlier window) >=2 barriers before its re-stage. vmcnt: 12 outstanding at
// W3 -> vmcnt(4) retires tile t+1's four halves, leaves B0/A0(t+2).

#define LSA0 (&Ls[0][0])
#define LSB0 (&Ls[0][16384])
#define LSA1 (&Ls[1][0])
#define LSB1 (&Ls[1][16384])

template<int NSPLIT>
__global__ __launch_bounds__(512, 2) void gemm_bt(
        const unsigned short* __restrict__ Ashuf,  // [256 rg][256 kb][64][8]
        const unsigned short* __restrict__ Bshuf,  // [64 cg][256 kb][64][8]
        float* __restrict__ C,                     // [4096][1024]
        unsigned short* __restrict__ P) {          // bf16 partials (splits 1..)
    constexpr int NT2 = NTT / NSPLIT;              // K-tiles per block
    static_assert((NT2 & 1) == 0, "loop assumes even NT2");
    __shared__ unsigned short Ls[2][32768];        // 128 KiB

    const int tid  = threadIdx.x;
    const int w    = tid >> 6;                     // 0..7
    const int lane = tid & 63;
    const int wm   = w >> 2, wn = w & 3;
    const int kkw  = w & 1, wh = w >> 1;           // staging roles
    const int lane8 = lane * 8;

    const int bid  = blockIdx.x;
    const int s    = bid & (NSPLIT - 1);
    const int tile = bid / NSPLIT;                 // 0..63
    const int mb16 = (tile >> 2) * 16;             // A rg base
    const int nb16 = (tile & 3) * 16;              // B cg base
    const int T0   = s * NT2;
    const int brow = mb16 * 16, bcol = nb16 * 16;

#define STAGE_OP(BASE, NB16, H, T, LS) do {                                   \
        size_t _kq = ((size_t)(2 * (T0 + (T)) + kkw)) * 512 + lane8;          \
        const unsigned short* _g = (BASE) + ((size_t)((NB16) + (H)*8 + wh) << 17) + _kq; \
        unsigned short* _l = (LS) + (((H)*16 + w) << 9);                      \
        gload_lds16(_g, _l);                                                  \
        gload_lds16(_g + ((size_t)4 << 17), _l + (8 << 9));                   \
    } while (0)
#define STAGE_A(H, T, LS) STAGE_OP(Ashuf, mb16, H, T, LS)
#define STAGE_B(H, T, LS) STAGE_OP(Bshuf, nb16, H, T, LS)

#define LDA_F(DST, H, LS) do {                                                \
        _Pragma("unroll")                                                     \
        for (int mf = 0; mf < 4; ++mf)                                        \
            _Pragma("unroll")                                                 \
            for (int kk = 0; kk < 2; ++kk)                                    \
                DST[mf][kk] = *reinterpret_cast<const short8*>(               \
                    (LS) + (((((H)*8 + wm*4 + mf) * 2) + kk) << 9) + lane8);  \
    } while (0)
#define LDB_F(DST, V, LS) do {                                                \
        _Pragma("unroll")                                                     \
        for (int nf = 0; nf < 2; ++nf)                                        \
            _Pragma("unroll")                                                 \
            for (int kk = 0; kk < 2; ++kk)                                    \
                DST[nf][kk] = *reinterpret_cast<const short8*>(               \
                    (LS) + (((((V)*8 + wn*2 + nf) * 2) + kk) << 9) + lane8);  \
    } while (0)

    f32x4 acc[8][4] = {};                          // [H*4+mf][V*2+nf]
    short8 aF[4][2], bv0[2][2], bv1[2][2];

#define MFMA_Q(H, V, AF, BV) do {                                             \
        __builtin_amdgcn_s_setprio(1);                                        \
        _Pragma("unroll")                                                     \
        for (int kk = 0; kk < 2; ++kk)                                        \
            _Pragma("unroll")                                                 \
            for (int mf = 0; mf < 4; ++mf)                                    \
                _Pragma("unroll")                                             \
                for (int nf = 0; nf < 2; ++nf)                                \
                    acc[(H)*4 + mf][(V)*2 + nf] =                             \
                        __builtin_amdgcn_mfma_f32_16x16x32_bf16(              \
                            AF[mf][kk], BV[nf][kk],                           \
                            acc[(H)*4 + mf][(V)*2 + nf], 0, 0, 0);            \
        __builtin_amdgcn_s_setprio(0);                                        \
    } while (0)

    // Pipelined tile: MFMA first (pre-read operands), reads/stages trail.
#define TILE(T, LAC, LBC, LAN, LBN, S1F, S23F, RN, VC) do {                   \
        __builtin_amdgcn_s_barrier();                                         \
        MFMA_Q(0, 0, aF, bv0);                                                \
        LDB_F(bv1, 1, LBC);                                                   \
        if (S1F) { STAGE_B(1, (T) + 1, LBN); STAGE_A(1, (T) + 1, LAN); }      \
        __builtin_amdgcn_s_barrier();                                         \
        MFMA_Q(0, 1, aF, bv1);                                                \
        LDA_F(aF, 1, LAC);                                                    \
        if (S23F) STAGE_B(0, (T) + 2, LBC);                                   \
        __builtin_amdgcn_s_barrier();                                         \
        MFMA_Q(1, 0, aF, bv0);                                                \
        if (S23F) STAGE_A(0, (T) + 2, LAC);                                   \
        asm volatile("s_waitcnt vmcnt(" VC ")" ::: "memory");                 \
        __builtin_amdgcn_s_barrier();                                         \
        MFMA_Q(1, 1, aF, bv1);                                                \
        if (RN) { LDA_F(aF, 0, LAN); LDB_F(bv0, 0, LBN); }                    \
    } while (0)

    // prologue: 12 gloads (tile0's 4 halves + tile1's B0/A0); publish tile 0;
    // pre-read tile0's A0/bv0 (the "W4(-1)" of the pipeline).
    STAGE_B(0, 0, LSB0); STAGE_A(0, 0, LSA0);
    STAGE_B(1, 0, LSB0); STAGE_A(1, 0, LSA0);
    STAGE_B(0, 1, LSB1); STAGE_A(0, 1, LSA1);
    asm volatile("s_waitcnt vmcnt(4)" ::: "memory");
    __builtin_amdgcn_s_barrier();
    LDA_F(aF, 0, LSA0); LDB_F(bv0, 0, LSB0);

#pragma unroll 1
    for (int t = 0; t + 2 <= NT2 - 2; t += 2) {
        TILE(t,     LSA0, LSB0, LSA1, LSB1, 1, 1, 1, "4");
        TILE(t + 1, LSA1, LSB1, LSA0, LSB0, 1, 1, 1, "4");
    }
    TILE(NT2 - 2, LSA0, LSB0, LSA1, LSB1, 1, 0, 1, "0");
    TILE(NT2 - 1, LSA1, LSB1, LSA0, LSB0, 0, 0, 0, "0");

    // epilogue: C/D layout col=lane&15, row=(lane>>4)*4+reg (m89-verified)
    // s==0 -> f32 to C; s>0 -> bf16 partial slab (reduce kernel sums).
    const int q4 = (lane >> 4) * 4, frow = lane & 15;
    if (NSPLIT == 1 || s == 0) {
#pragma unroll
        for (int H = 0; H < 2; ++H)
#pragma unroll
            for (int mf = 0; mf < 4; ++mf)
#pragma unroll
                for (int V = 0; V < 2; ++V)
#pragma unroll
                    for (int nf = 0; nf < 2; ++nf)
#pragma unroll
                        for (int r = 0; r < 4; ++r) {
                            int row = brow + H * 128 + wm * 64 + mf * 16 + q4 + r;
                            int col = bcol + V * 128 + wn * 32 + nf * 16 + frow;
                            C[(size_t)row * OUTN + col] = acc[H * 4 + mf][V * 2 + nf][r];
                        }
    } else {
        unsigned short* Pb = P + (size_t)(s - 1) * BATCH * OUTN;
#pragma unroll
        for (int H = 0; H < 2; ++H)
#pragma unroll
            for (int mf = 0; mf < 4; ++mf)
#pragma unroll
                for (int V = 0; V < 2; ++V)
#pragma unroll
                    for (int nf = 0; nf < 2; ++nf)
#pragma unroll
                        for (int r = 0; r < 4; ++r) {
                            int row = brow + H * 128 + wm * 64 + mf * 16 + q4 + r;
                            int col = bcol + V * 128 + wn * 32 + nf * 16 + frow;
                            Pb[(size_t)row * OUTN + col] = f2bf(acc[H * 4 + mf][V * 2 + nf][r]);
                        }
    }
}

// ---------- kernel 3: C += sum of np bf16 partials ----------

__global__ void reduce_kernel(float* __restrict__ C, const unsigned short* __restrict__ P,
                              int np) {
    int i = blockIdx.x * 256 + threadIdx.x;        // 524,288 threads x 8 f32
    size_t base = (size_t)i * 8;
    f32x4 c0 = *reinterpret_cast<f32x4*>(&C[base]);
    f32x4 c1 = *reinterpret_cast<f32x4*>(&C[base + 4]);
    for (int j = 0; j < np; ++j) {
        ushort8 p = *reinterpret_cast<const ushort8*>(&P[(size_t)j * BATCH * OUTN + base]);
#pragma unroll
        for (int e = 0; e < 4; ++e) c0[e] += bf2f(p[e]);
#pragma unroll
        for (int e = 0; e < 4; ++e) c1[e] += bf2f(p[4 + e]);
    }
    *reinterpret_cast<f32x4*>(&C[base])     = c0;
    *reinterpret_cast<f32x4*>(&C[base + 4]) = c1;
}

// ---------- launch ----------

extern "C" void kernel_launch(void* const* d_in, const int* in_sizes, int n_in,
                              void* d_out, int out_size, void* d_ws, size_t ws_size,
                              hipStream_t stream) {
    const float* x    = (const float*)d_in[0];
    const float* coef = (const float*)d_in[1];
    float* out = (float*)d_out;

    // ws: [A_shuf 64 MiB][B_shuf 16 MiB][bf16 partials 8 MiB x (NSPLIT-1)]
    unsigned short* ashuf = (unsigned short*)d_ws;
    unsigned short* bshuf = ashuf + (size_t)BATCH * KDIM;
    unsigned short* part  = bshuf + (size_t)OUTN * KDIM;
    const size_t base = (size_t)BATCH * KDIM * 2 + (size_t)OUTN * KDIM * 2;  // 80 MiB
    const size_t slab = (size_t)BATCH * OUTN * 2;                            // 8 MiB

    prep_kernel<<<5120, 256, 0, stream>>>(x, coef, ashuf, bshuf);

    if (ws_size >= base + 3 * slab) {
        gemm_bt<4><<<256, 512, 0, stream>>>(ashuf, bshuf, out, part);
        reduce_kernel<<<2048, 256, 0, stream>>>(out, part, 3);
    } else if (ws_size >= base + slab) {
        gemm_bt<2><<<128, 512, 0, stream>>>(ashuf, bshuf, out, part);
        reduce_kernel<<<2048, 256, 0, stream>>>(out, part, 1);
    } else {
        gemm_bt<1><<<64, 512, 0, stream>>>(ashuf, bshuf, out, nullptr);
    }
}